// Round 3
// 478.943 us; speedup vs baseline: 1.0864x; 1.0864x over previous
//
#include <hip/hip_runtime.h>
#include <hip/hip_fp16.h>

// GCN encoder, restructured:
//   Y1 = fp16(x @ W1)                   MFMA f16 (fp32 acc), [N,256]x[256,128]
//   Y2 = fp16(relu(b1 + spmm(Y1)) @ W2) spmm128 w/ FUSED matvec epilogue
//                                       (H1 never materialized)
//   out = b2 + spmm(Y2)                 (CSR wave-per-row, F=64)
// spmm(x)@W == spmm(x@W) (linearity); biases folded into spmm accumulators.
//
// CSR build (every call; d_ws poisoned by harness):
//   bucket_hist (LDS-privatized, 209 buckets of 480 rows) -> bucket_scan
//   -> partition (coarse multisplit) -> fine_scatter (1024 thr/block).
// Round-3 lesson: spmm stays high-occupancy/low-LDS (TLP hides gather latency).
// Round-5 lesson: fp32 VALU GEMM had 1.28e7 LDS bank conflicts -> MFMA fp16.
// Round-6 lesson: millions of random global atomics write ~32B/op to HBM.
// Round-7 lesson: scatter run length = PCHUNK/nB; keep runs fat.
// Round-8 lesson: spmm128 gather is at the per-CU random-gather ceiling
// (~12B/cy/CU); fused gemm2 into the spmm epilogue.
// Round-9: G-lanes-per-edge dwordx4 gathers (4 edges/VMEM instr at F=128,
// 8 at F=64; same cache lines, 4-8x fewer VMEM instrs + fewer shfl/cvt).
// Round-11 lesson (rounds 9-10 FAILED, absmax ~21): __shfl under a PER-LANE
// predicate ( cond ? __shfl(v, s) : 0 ) exec-masks the ds_bpermute; pulling
// from a source lane that is INACTIVE in that branch returns undefined/zero
// (e.g. n=21, j=16: reader g=0 pulls lane 20, whose own i1'=21>=n makes it
// inactive). Rule: issue every __shfl with full wave-uniform EXEC, mask the
// RESULT afterward with a register select. (Round-10's plain-h2t LDS stores
// for the barrier-less handoff are kept -- still required for ordering.)

#define RPB 480      // rows per coarse bucket (rowlocal fits 9 bits)
#define NB_MAX 1024  // bucket capacity in partition LDS
#define PCHUNK 8192  // edges per partition block (256 thr x 32)
#define EPT 32       // edges per thread in partition

typedef _Float16 half8 __attribute__((ext_vector_type(8)));
typedef _Float16 h2t __attribute__((ext_vector_type(2)));
typedef float floatx4 __attribute__((ext_vector_type(4)));

// ---------------------------------------------------------------- weight prep (fast path)
// W1T[n][k] = fp16(W1[k][n]) (for MFMA gemm1); pk[kk*64+c] = (W2[2kk][c], W2[2kk+1][c]) fp16
// tail threads: zero gcnt (saves a dispatch)
__global__ __launch_bounds__(256) void prep_weights_kernel(const float* __restrict__ W1,
                                                           const float* __restrict__ W2,
                                                           __half* __restrict__ W1T,
                                                           h2t* __restrict__ pk,
                                                           int* __restrict__ gcnt) {
    int i = blockIdx.x * 256 + threadIdx.x;
    if (i < 256 * 128) {
        int k = i >> 7, n = i & 127;
        W1T[n * 256 + k] = __float2half_rn(W1[i]);
    } else if (i < 256 * 128 + 4096) {
        int j = i - 256 * 128;
        int kk = j >> 6, c = j & 63;
        h2t v;
        v[0] = (_Float16)W2[(2 * kk) * 64 + c];
        v[1] = (_Float16)W2[(2 * kk + 1) * 64 + c];
        pk[j] = v;
    } else {
        int j = i - (256 * 128 + 4096);
        if (j < NB_MAX) gcnt[j] = 0;
    }
}

// ---------------------------------------------------------------- W transpose+cast (fallback)
__global__ __launch_bounds__(256) void transpose_w_kernel(const float* __restrict__ W,
                                                          __half* __restrict__ WT,
                                                          int K, int N) {
    int i = blockIdx.x * 256 + threadIdx.x;
    if (i < K * N) {
        int k = i / N, n = i % N;
        WT[n * K + k] = __float2half_rn(W[i]);
    }
}

// ---------------------------------------------------------------- bucket histogram (LDS-privatized)
__global__ __launch_bounds__(256) void bucket_hist_kernel(const int* __restrict__ rows,
                                                          int* __restrict__ gcnt,
                                                          int nE, int nB) {
    __shared__ int hist[NB_MAX];
    const int t = threadIdx.x;
    const int c0 = blockIdx.x * PCHUNK;
    const int c1 = min(c0 + PCHUNK, nE);
    for (int b = t; b < nB; b += 256) hist[b] = 0;
    __syncthreads();
    for (int e = c0 + t; e < c1; e += 256) atomicAdd(&hist[rows[e] / RPB], 1);
    __syncthreads();
    for (int b = t; b < nB; b += 256) {
        int c = hist[b];
        if (c) atomicAdd(&gcnt[b], c);
    }
}

// ---------------------------------------------------------------- bucket scan (1 small block)
__global__ __launch_bounds__(1024) void bucket_scan_kernel(const int* __restrict__ gcnt,
                                                           int* __restrict__ boff,
                                                           int* __restrict__ gcur,
                                                           int* __restrict__ off,
                                                           int nB, int nN) {
    __shared__ int part[1024];
    int t = threadIdx.x;
    int v = (t < nB) ? gcnt[t] : 0;
    part[t] = v;
    __syncthreads();
    for (int d = 1; d < 1024; d <<= 1) {
        int add = (t >= d) ? part[t - d] : 0;
        __syncthreads();
        part[t] += add;
        __syncthreads();
    }
    if (t < nB) {
        int excl = part[t] - v;
        boff[t] = excl;
        gcur[t] = excl;
    }
    if (t == 1023) {
        boff[nB] = part[1023];
        off[nN] = part[1023];
    }
}

// ---------------------------------------------------------------- coarse multisplit partition
// payload: (col | rowlocal<<17, val). Requires col < 2^17, rowlocal < 512.
__global__ __launch_bounds__(256) void partition_kernel(const int* __restrict__ rows,
                                                        const int* __restrict__ cols,
                                                        const float* __restrict__ vals,
                                                        int* __restrict__ gcur,
                                                        int2* __restrict__ eb1,
                                                        int nE, int nB) {
    __shared__ int hist[NB_MAX];
    __shared__ int cur[NB_MAX];
    const int t = threadIdx.x;
    const int c0 = blockIdx.x * PCHUNK;
    for (int b = t; b < nB; b += 256) hist[b] = 0;
    __syncthreads();
    int myr[EPT];
#pragma unroll
    for (int j = 0; j < EPT; ++j) {
        int e = c0 + t + 256 * j;
        int r = (e < nE) ? rows[e] : -1;
        myr[j] = r;
        if (r >= 0) atomicAdd(&hist[r / RPB], 1);
    }
    __syncthreads();
    for (int b = t; b < nB; b += 256) {
        int c = hist[b];
        cur[b] = c ? atomicAdd(&gcur[b], c) : 0;
    }
    __syncthreads();
#pragma unroll
    for (int j = 0; j < EPT; ++j) {
        int r = myr[j];
        if (r >= 0) {
            int e = c0 + t + 256 * j;
            int bk = r / RPB;
            int rl = r - bk * RPB;
            int pos = atomicAdd(&cur[bk], 1);
            eb1[pos] = make_int2((cols[e] & 0x1FFFF) | (rl << 17), __float_as_int(vals[e]));
        }
    }
}

// ---------------------------------------------------------------- fine scatter + off writer
__global__ __launch_bounds__(1024) void fine_scatter_kernel(const int* __restrict__ boff,
                                                            const int2* __restrict__ eb1,
                                                            int2* __restrict__ eb2,
                                                            int* __restrict__ off,
                                                            int nN) {
    __shared__ int hist[RPB];
    __shared__ int sc[RPB];
    __shared__ int cur[RPB];
    const int b = blockIdx.x;
    const int row0 = b * RPB;
    const int nr = min(RPB, nN - row0);
    const int t = threadIdx.x;
    const int s = boff[b];
    const int e = boff[b + 1];

    if (t < RPB) hist[t] = 0;
    __syncthreads();
    for (int i = s + t; i < e; i += 1024)
        atomicAdd(&hist[((unsigned)eb1[i].x) >> 17], 1);
    __syncthreads();

    int myc = (t < RPB) ? hist[t] : 0;
    if (t < RPB) sc[t] = myc;
    __syncthreads();
    for (int d = 1; d < RPB; d <<= 1) {
        int add = (t < RPB && t >= d) ? sc[t - d] : 0;
        __syncthreads();
        if (t < RPB) sc[t] += add;
        __syncthreads();
    }
    if (t < RPB) {
        int excl = s + sc[t] - myc;
        cur[t] = excl;
        if (t < nr) off[row0 + t] = excl;
    }
    __syncthreads();

    for (int i = s + t; i < e; i += 1024) {
        int2 ed = eb1[i];
        unsigned x = (unsigned)ed.x;
        int pos = atomicAdd(&cur[x >> 17], 1);
        eb2[pos] = make_int2((int)(x & 0x1FFFF), ed.y);
    }
}

// ---------------------------------------------------------------- FUSED spmm128 + matvec
// Wave = 1 row. Gather: lane = (edge-subgroup g = lane>>4, feature-group
// fg = lane&15). One dwordx4 load covers 4 edges' rows (16 lanes x 16B =
// 256B/row); per lane 8 fp16 features, fp32 acc[8]. End of row:
// shfl_xor(16,32) combines the 4 edge-subgroups, then bias+relu, pack to
// LDS (plain h2t stores), per-row matvec by W2.
// ALL __shfl issued with full wave-uniform EXEC; results masked after.
__global__ __launch_bounds__(256) void spmm_fused_kernel(const int* __restrict__ off,
                                                         const int2* __restrict__ eb,
                                                         const __half* __restrict__ Y,
                                                         const float* __restrict__ b1,
                                                         const h2t* __restrict__ pk,
                                                         __half* __restrict__ Y2, int nN) {
    __shared__ h2t w2s[64 * 64];  // w2s[kk*64+c] = (W2[2kk][c], W2[2kk+1][c])
    __shared__ h2t hs[4][64];     // per-wave relu'd H1 row, packed pairs
    const int t = threadIdx.x;
#pragma unroll
    for (int i = 0; i < 16; ++i) w2s[i * 256 + t] = pk[i * 256 + t];
    __syncthreads();

    const int row = blockIdx.x * 4 + (t >> 6);
    const int wv = t >> 6;
    const int lane = t & 63;

    if (row < nN) {
        const int fg = lane & 15;  // feature group: 8 halfs at fg*8
        const int g = lane >> 4;   // edge subgroup 0..3
        float acc[8];
#pragma unroll
        for (int p = 0; p < 8; ++p) acc[p] = 0.f;

        int s = off[row];
        int e1 = off[row + 1];
        for (int base = s; base < e1; base += 64) {
            int n = min(64, e1 - base);
            int2 my = (lane < n) ? eb[base + lane] : make_int2(0, 0);
            for (int j = 0; j < n; j += 8) {
                int i0 = j + g;
                int i1 = j + 4 + g;
                // clamp invalid subgroup indices onto edge j (same cache
                // lines, valid source lane); contribution zeroed via val.
                int s0 = (i0 < n) ? i0 : j;
                int s1 = (i1 < n) ? i1 : j;
                // UNCONDITIONAL shuffles (full EXEC); mask results after.
                int c0 = __shfl(my.x, s0);
                int c1 = __shfl(my.x, s1);
                float v0 = __int_as_float(__shfl(my.y, s0));
                float v1 = __int_as_float(__shfl(my.y, s1));
                if (i0 >= n) v0 = 0.f;
                if (i1 >= n) v1 = 0.f;
                half8 y0 = *(const half8*)(Y + ((size_t)c0 << 7) + (fg << 3));
                half8 y1 = *(const half8*)(Y + ((size_t)c1 << 7) + (fg << 3));
#pragma unroll
                for (int p = 0; p < 8; ++p) acc[p] = fmaf(v0, (float)y0[p], acc[p]);
#pragma unroll
                for (int p = 0; p < 8; ++p) acc[p] = fmaf(v1, (float)y1[p], acc[p]);
            }
        }
        // combine the 4 edge-subgroups (lanes differ in bits 4,5 only)
#pragma unroll
        for (int p = 0; p < 8; ++p) acc[p] += __shfl_xor(acc[p], 16);
#pragma unroll
        for (int p = 0; p < 8; ++p) acc[p] += __shfl_xor(acc[p], 32);

        // bias + relu + pack into per-wave LDS. PLAIN element-type (h2t)
        // stores only (barrier-less wave-synchronous handoff).
        if (g == 0) {
            floatx4 ba = *(const floatx4*)(b1 + fg * 8);
            floatx4 bb = *(const floatx4*)(b1 + fg * 8 + 4);
            float f[8];
#pragma unroll
            for (int p = 0; p < 4; ++p) f[p] = fmaxf(acc[p] + ba[p], 0.f);
#pragma unroll
            for (int p = 0; p < 4; ++p) f[4 + p] = fmaxf(acc[4 + p] + bb[p], 0.f);
#pragma unroll
            for (int p = 0; p < 4; ++p) {
                h2t pr;
                pr[0] = (_Float16)f[2 * p];
                pr[1] = (_Float16)f[2 * p + 1];
                hs[wv][fg * 4 + p] = pr;  // hs[wv][i] = features (2i, 2i+1)
            }
        }
        __builtin_amdgcn_sched_barrier(0);  // pin handoff order

        // matvec: o = sum_kk dot2(hs[kk], W2pair[kk][lane])
        // (same-wave DS ordering: no barrier needed)
        float o = 0.f;
#pragma unroll 8
        for (int kk = 0; kk < 64; ++kk) {
            h2t a = hs[wv][kk];           // LDS broadcast (free)
            h2t b = w2s[kk * 64 + lane];  // 2-way bank aliasing (free)
#if __has_builtin(__builtin_amdgcn_fdot2)
            o = __builtin_amdgcn_fdot2(a, b, o, false);
#else
            o = fmaf((float)a[0], (float)b[0], o);
            o = fmaf((float)a[1], (float)b[1], o);
#endif
        }
        Y2[(size_t)row * 64 + lane] = __float2half_rn(o);
    }
}

// ---------------------------------------------------------------- CSR spmm F=64 (final layer)
// Wave = 1 row, 8-lanes-per-edge dwordx4 gather: one load covers 8 edges'
// 128B rows (8 lanes x 16B); acc[8] fp32; shfl_xor(8,16,32) combines the 8
// edge-subgroups; lanes 0..7 write 256B coalesced fp32.
// ALL __shfl issued with full wave-uniform EXEC; results masked after.
__global__ __launch_bounds__(256) void spmm_csr64_kernel(const int* __restrict__ off,
                                                         const int2* __restrict__ eb,
                                                         const __half* __restrict__ Y,
                                                         const float* __restrict__ bias,
                                                         float* __restrict__ out, int nN) {
    int row = blockIdx.x * 4 + (threadIdx.x >> 6);
    if (row >= nN) return;
    int lane = threadIdx.x & 63;
    const int fg = lane & 7;  // 8 features at fg*8
    const int g = lane >> 3;  // edge subgroup 0..7

    float acc[8];
#pragma unroll
    for (int p = 0; p < 8; ++p) acc[p] = 0.f;

    int s = off[row];
    int e1 = off[row + 1];
    for (int base = s; base < e1; base += 64) {
        int n = min(64, e1 - base);
        int2 my = (lane < n) ? eb[base + lane] : make_int2(0, 0);
        for (int j = 0; j < n; j += 16) {
            int i0 = j + g;
            int i1 = j + 8 + g;
            int s0 = (i0 < n) ? i0 : j;
            int s1 = (i1 < n) ? i1 : j;
            int c0 = __shfl(my.x, s0);
            int c1 = __shfl(my.x, s1);
            float v0 = __int_as_float(__shfl(my.y, s0));
            float v1 = __int_as_float(__shfl(my.y, s1));
            if (i0 >= n) v0 = 0.f;
            if (i1 >= n) v1 = 0.f;
            half8 y0 = *(const half8*)(Y + ((size_t)c0 << 6) + (fg << 3));
            half8 y1 = *(const half8*)(Y + ((size_t)c1 << 6) + (fg << 3));
#pragma unroll
            for (int p = 0; p < 8; ++p) acc[p] = fmaf(v0, (float)y0[p], acc[p]);
#pragma unroll
            for (int p = 0; p < 8; ++p) acc[p] = fmaf(v1, (float)y1[p], acc[p]);
        }
    }
    // combine the 8 edge-subgroups (lanes differ in bits 3,4,5 only)
#pragma unroll
    for (int p = 0; p < 8; ++p) acc[p] += __shfl_xor(acc[p], 8);
#pragma unroll
    for (int p = 0; p < 8; ++p) acc[p] += __shfl_xor(acc[p], 16);
#pragma unroll
    for (int p = 0; p < 8; ++p) acc[p] += __shfl_xor(acc[p], 32);

    if (g == 0) {
        floatx4 ba = *(const floatx4*)(bias + fg * 8);
        floatx4 bb = *(const floatx4*)(bias + fg * 8 + 4);
        floatx4 o0, o1;
#pragma unroll
        for (int p = 0; p < 4; ++p) o0[p] = acc[p] + ba[p];
#pragma unroll
        for (int p = 0; p < 4; ++p) o1[p] = acc[4 + p] + bb[p];
        float* op = out + (size_t)row * 64 + fg * 8;
        *(floatx4*)op = o0;
        *(floatx4*)(op + 4) = o1;
    }
}

// ---------------------------------------------------------------- fallback atomic path
__global__ __launch_bounds__(256) void init_bias_kernel(float* __restrict__ out,
                                                        const float* __restrict__ bias,
                                                        int fmask, size_t total) {
    size_t i = (size_t)blockIdx.x * 256 + threadIdx.x;
    if (i < total) out[i] = bias[i & fmask];
}

template <int F>
__global__ __launch_bounds__(256) void spmm_atomic_kernel(const int* __restrict__ rows,
                                                          const int* __restrict__ cols,
                                                          const float* __restrict__ vals,
                                                          const __half* __restrict__ Y,
                                                          float* __restrict__ out, int nE) {
    int e = blockIdx.x * 4 + (threadIdx.x >> 6);
    if (e >= nE) return;
    int lane = threadIdx.x & 63;
    int r = rows[e];
    int c = cols[e];
    float v = vals[e];
    if (F == 128) {
        float2 y = __half22float2(*((const __half2*)(Y + (size_t)c * 128) + lane));
        float* op = out + (size_t)r * 128 + lane * 2;
        unsafeAtomicAdd(op, v * y.x);
        unsafeAtomicAdd(op + 1, v * y.y);
    } else {
        float y = __half2float(Y[(size_t)c * F + lane]);
        unsafeAtomicAdd(out + (size_t)r * F + lane, v * y);
    }
}

// ---------------------------------------------------------------- MFMA fp16 GEMM
// C[nrows,NN] (fp16) = (RELU_IN ? relu(A) : A)[nrows,KK] (fp32) @ B[KK,NN]
template <int NN, int KK, bool RELU_IN>
__global__ __launch_bounds__(256) void gemm_mfma_kernel(const float* __restrict__ A,
                                                        const __half* __restrict__ BT,
                                                        __half* __restrict__ C, int nrows) {
    constexpr int MT = 64, KT = 64, KP = KT + 8;
    __shared__ __half As[MT * KP];
    __shared__ __half Bs[NN * KP];
    const int tid = threadIdx.x;
    const int wid = tid >> 6, lane = tid & 63;
    const int row0 = blockIdx.x * MT;
    const int wr = wid & 1, wc = wid >> 1;
    constexpr int WCT = NN / 32;
    const int lrow = lane & 15, q = lane >> 4;

    floatx4 acc[2][WCT];
#pragma unroll
    for (int rt = 0; rt < 2; ++rt)
#pragma unroll
        for (int ct = 0; ct < WCT; ++ct)
#pragma unroll
            for (int i = 0; i < 4; ++i) acc[rt][ct][i] = 0.f;

    for (int kt = 0; kt < KK; kt += KT) {
#pragma unroll
        for (int it = 0; it < MT * KT / 4 / 256; ++it) {
            int i4 = it * 256 + tid;
            int m = i4 >> 4;
            int kk = (i4 & 15) << 2;
            int gr = row0 + m;
            float4 v = make_float4(0.f, 0.f, 0.f, 0.f);
            if (gr < nrows) v = *(const float4*)(A + (size_t)gr * KK + kt + kk);
            if (RELU_IN) {
                v.x = fmaxf(v.x, 0.f); v.y = fmaxf(v.y, 0.f);
                v.z = fmaxf(v.z, 0.f); v.w = fmaxf(v.w, 0.f);
            }
            __half h0 = __float2half_rn(v.x), h1 = __float2half_rn(v.y);
            __half h2 = __float2half_rn(v.z), h3 = __float2half_rn(v.w);
            ushort4 u = make_ushort4(*(unsigned short*)&h0, *(unsigned short*)&h1,
                                     *(unsigned short*)&h2, *(unsigned short*)&h3);
            *(ushort4*)(As + m * KP + kk) = u;
        }
#pragma unroll
        for (int it = 0; it < NN * KT / 4 / 256; ++it) {
            int i4 = it * 256 + tid;
            int n = i4 >> 4;
            int kk = (i4 & 15) << 2;
            *(ushort4*)(Bs + n * KP + kk) =
                *(const ushort4*)(BT + (size_t)n * KK + kt + kk);
        }
        __syncthreads();

#pragma unroll
        for (int ks = 0; ks < KT; ks += 32) {
            half8 a0 = *(half8*)(As + (wr * 32 + lrow) * KP + ks + q * 8);
            half8 a1 = *(half8*)(As + (wr * 32 + 16 + lrow) * KP + ks + q * 8);
#pragma unroll
            for (int ct = 0; ct < WCT; ++ct) {
                half8 b = *(half8*)(Bs + (wc * (NN / 2) + ct * 16 + lrow) * KP + ks + q * 8);
                acc[0][ct] = __builtin_amdgcn_mfma_f32_16x16x32_f16(a0, b, acc[0][ct], 0, 0, 0);
                acc[1][ct] = __builtin_amdgcn_mfma_f32_16x16x32_f16(a1, b, acc[1][ct], 0, 0, 0);
            }
        }
        __syncthreads();
    }

#pragma unroll
    for (int rt = 0; rt < 2; ++rt)
#pragma unroll
        for (int ct = 0; ct < WCT; ++ct)
#pragma unroll
            for (int r = 0; r < 4; ++r) {
                int gr = row0 + wr * 32 + rt * 16 + q * 4 + r;
                if (gr < nrows)
                    C[(size_t)gr * NN + wc * (NN / 2) + ct * 16 + lrow] =
                        __float2half_rn(acc[rt][ct][r]);
            }
}

extern "C" void kernel_launch(void* const* d_in, const int* in_sizes, int n_in,
                              void* d_out, int out_size, void* d_ws, size_t ws_size,
                              hipStream_t stream) {
    const float* x    = (const float*)d_in[0];
    const int*   rows = (const int*)d_in[1];
    const int*   cols = (const int*)d_in[2];
    const float* vals = (const float*)d_in[3];
    const float* W1   = (const float*)d_in[4];
    const float* b1   = (const float*)d_in[5];
    const float* W2   = (const float*)d_in[6];
    const float* b2   = (const float*)d_in[7];
    float* out = (float*)d_out;

    const int nN = in_sizes[0] / 256;  // 100000
    const int nE = in_sizes[1];        // 3200000
    const int nB = (nN + RPB - 1) / RPB;

    // ws layout: Y1h | H1(fallback; fast path overlays Y2h here) | W1T | W2T |
    //            pk | off | gcnt | boff | gcur | eb1 | eb2
    char* w = (char*)d_ws;
    __half* Y1h = (__half*)w;   w += (size_t)nN * 128 * 2;
    float*  H1  = (float*)w;    w += (size_t)nN * 128 * 4;
    __half* Y2h = (__half*)H1;  // fast path: Y2 [nN*64 fp16] in H1's slot
    __half* W1T = (__half*)w;   w += (size_t)256 * 128 * 2;
    __half* W2T = (__half*)w;   w += (size_t)128 * 64 * 2;
    h2t*    pk  = (h2t*)w;      w += (size_t)4096 * 4;
    int*  off   = (int*)w;      w += ((size_t)nN + 4) * 4;
    int*  gcnt  = (int*)w;      w += (size_t)NB_MAX * 4;
    int*  boff  = (int*)w;      w += (size_t)(NB_MAX + 4) * 4;
    int*  gcur  = (int*)w;      w += (size_t)NB_MAX * 4;
    int2* eb1   = (int2*)w;     w += (size_t)nE * 8;
    int2* eb2   = (int2*)w;     w += (size_t)nE * 8;
    size_t need = (size_t)(w - (char*)d_ws);

    const int mblocks  = (nN + 63) / 64;
    const int pblocks  = (nE + PCHUNK - 1) / PCHUNK;
    const int rblocks  = (nN + 3) / 4;
    const int eblocks4 = (nE + 3) / 4;

    if (ws_size >= need && nN <= (1 << 17) && nB <= NB_MAX) {
        // ---- fast path ----
        prep_weights_kernel<<<(256 * 128 + 4096 + NB_MAX + 255) / 256, 256, 0, stream>>>(
            W1, W2, W1T, pk, gcnt);
        gemm_mfma_kernel<128, 256, false><<<mblocks, 256, 0, stream>>>(x, W1T, Y1h, nN);

        bucket_hist_kernel<<<pblocks, 256, 0, stream>>>(rows, gcnt, nE, nB);
        bucket_scan_kernel<<<1, 1024, 0, stream>>>(gcnt, boff, gcur, off, nB, nN);
        partition_kernel<<<pblocks, 256, 0, stream>>>(rows, cols, vals, gcur, eb1, nE, nB);
        fine_scatter_kernel<<<nB, 1024, 0, stream>>>(boff, eb1, eb2, off, nN);

        // Y2 = fp16(relu(b1 + spmm(Y1)) @ W2)   [fused]
        spmm_fused_kernel<<<rblocks, 256, 0, stream>>>(off, eb2, Y1h, b1, pk, Y2h, nN);
        // out = b2 + spmm(Y2)
        spmm_csr64_kernel<<<rblocks, 256, 0, stream>>>(off, eb2, Y2h, b2, out, nN);
    } else {
        // ---- fallback: atomic path ----
        transpose_w_kernel<<<(256 * 128 + 255) / 256, 256, 0, stream>>>(W1, W1T, 256, 128);
        transpose_w_kernel<<<(128 * 64 + 255) / 256, 256, 0, stream>>>(W2, W2T, 128, 64);
        gemm_mfma_kernel<128, 256, false><<<mblocks, 256, 0, stream>>>(x, W1T, Y1h, nN);
        size_t totH1 = (size_t)nN * 128;
        init_bias_kernel<<<(int)((totH1 + 255) / 256), 256, 0, stream>>>(H1, b1, 127, totH1);
        spmm_atomic_kernel<128><<<eblocks4, 256, 0, stream>>>(rows, cols, vals, Y1h, H1, nE);
        gemm_mfma_kernel<64, 128, true><<<mblocks, 256, 0, stream>>>(H1, W2T, Y1h, nN);
        size_t totOut = (size_t)nN * 64;
        init_bias_kernel<<<(int)((totOut + 255) / 256), 256, 0, stream>>>(out, b2, 63, totOut);
        spmm_atomic_kernel<64><<<eblocks4, 256, 0, stream>>>(rows, cols, vals, Y1h, out, nE);
    }
}

// Round 5
// 463.088 us; speedup vs baseline: 1.1236x; 1.0342x over previous
//
#include <hip/hip_runtime.h>
#include <hip/hip_fp16.h>

// GCN encoder:
//   Y1 = fp16(x @ W1)                   MFMA f16 (fp32 acc), [N,256]x[256,128]
//   Y2 = fp16(relu(b1 + spmm(Y1)) @ W2) spmm128 w/ FUSED matvec epilogue
//   out = b2 + spmm(Y2)                 (wave-per-row, F=64)
// spmm(x)@W == spmm(x@W) (linearity); biases folded into spmm accumulators.
//
// CSR build (every call; d_ws poisoned by harness), SLOTTED layout:
//   partition (coarse multisplit into per-bucket 16K-edge slots; gcnt is the
//   cursor AND final count) -> fine_scatter (1024 thr: LDS rowlocal hist(480)
//   + scan -> off2[] (start,len) + scatter into L2-resident slot window).
//   No bucket_hist / bucket_scan kernels; slot gaps are invisible to spmm
//   because rows carry (start,len).
// Round-3 lesson: spmm stays high-occupancy/low-LDS (TLP hides gather latency).
// Round-5 lesson: fp32 VALU GEMM had 1.28e7 LDS bank conflicts -> MFMA fp16.
// Round-6 lesson: millions of random global atomics write ~32B/op to HBM.
// Round-7 lesson: scatter run length = PCHUNK/nB; keep runs fat.
// Round-8/12 lesson: spmm gathers run at the per-CU random-gather ceiling
// (~12 B/cy/CU): fused=113us for 819MB, csr64 ~57us for 410MB. Gather floor
// for both layers ~167us. Remaining spmm cost is AROUND the gather: w2s
// refill per block (400MB of pk traffic at 25000 blocks) and Poisson tail
// imbalance -> grid-stride waves (2048 blocks), w2s loaded once per block.
// Round-11 lesson: __shfl under a per-lane predicate exec-masks ds_bpermute;
// pulling from an inactive source lane is undefined. Issue shuffles with
// full EXEC, mask the RESULT.
// Round-10 lesson: barrier-less wave-synchronous LDS handoff requires plain
// element-type stores (type-punned wide stores get TBAA-reordered).
// Round-13: round-12 bench was an infra failure (container died before
// compile); identical resubmission.

#define RPB 480        // rows per coarse bucket (rowlocal fits 9 bits)
#define NB_MAX 1024    // max buckets
#define PCHUNK 8192    // edges per partition block (256 thr x 32)
#define EPT 32         // edges per thread in partition
#define CAP_SHIFT 14   // 16384-edge slot per bucket (mean 15311 @ nE=3.2M)
#define CAP (1 << CAP_SHIFT)

typedef _Float16 half8 __attribute__((ext_vector_type(8)));
typedef _Float16 h2t __attribute__((ext_vector_type(2)));
typedef float floatx4 __attribute__((ext_vector_type(4)));

// ---------------------------------------------------------------- weight prep (fast path)
// W1T[n][k] = fp16(W1[k][n]); pk[kk*64+c] = (W2[2kk][c], W2[2kk+1][c]) fp16
// tail threads: zero gcnt (partition's slot cursors)
__global__ __launch_bounds__(256) void prep_weights_kernel(const float* __restrict__ W1,
                                                           const float* __restrict__ W2,
                                                           __half* __restrict__ W1T,
                                                           h2t* __restrict__ pk,
                                                           int* __restrict__ gcnt) {
    int i = blockIdx.x * 256 + threadIdx.x;
    if (i < 256 * 128) {
        int k = i >> 7, n = i & 127;
        W1T[n * 256 + k] = __float2half_rn(W1[i]);
    } else if (i < 256 * 128 + 4096) {
        int j = i - 256 * 128;
        int kk = j >> 6, c = j & 63;
        h2t v;
        v[0] = (_Float16)W2[(2 * kk) * 64 + c];
        v[1] = (_Float16)W2[(2 * kk + 1) * 64 + c];
        pk[j] = v;
    } else {
        int j = i - (256 * 128 + 4096);
        if (j < NB_MAX) gcnt[j] = 0;
    }
}

// ---------------------------------------------------------------- W transpose+cast (fallback)
__global__ __launch_bounds__(256) void transpose_w_kernel(const float* __restrict__ W,
                                                          __half* __restrict__ WT,
                                                          int K, int N) {
    int i = blockIdx.x * 256 + threadIdx.x;
    if (i < K * N) {
        int k = i / N, n = i % N;
        WT[n * K + k] = __float2half_rn(W[i]);
    }
}

// ---------------------------------------------------------------- coarse multisplit partition
// payload: (col | rowlocal<<17, val). Requires col < 2^17, rowlocal < 512.
// Writes into per-bucket slot [b<<CAP_SHIFT, b<<CAP_SHIFT + CAP); gcnt[b] is
// the slot cursor (ends as the bucket count).
__global__ __launch_bounds__(256) void partition_kernel(const int* __restrict__ rows,
                                                        const int* __restrict__ cols,
                                                        const float* __restrict__ vals,
                                                        int* __restrict__ gcnt,
                                                        int2* __restrict__ eb1,
                                                        int nE, int nB) {
    __shared__ int hist[NB_MAX];
    __shared__ int cur[NB_MAX];
    const int t = threadIdx.x;
    const int c0 = blockIdx.x * PCHUNK;
    for (int b = t; b < nB; b += 256) hist[b] = 0;
    __syncthreads();
    int myr[EPT];
#pragma unroll
    for (int j = 0; j < EPT; ++j) {
        int e = c0 + t + 256 * j;
        int r = (e < nE) ? rows[e] : -1;
        myr[j] = r;
        if (r >= 0) atomicAdd(&hist[r / RPB], 1);
    }
    __syncthreads();
    for (int b = t; b < nB; b += 256) {
        int c = hist[b];
        cur[b] = c ? (b << CAP_SHIFT) + atomicAdd(&gcnt[b], c) : 0;
    }
    __syncthreads();
#pragma unroll
    for (int j = 0; j < EPT; ++j) {
        int r = myr[j];
        if (r >= 0) {
            int e = c0 + t + 256 * j;
            int bk = r / RPB;
            int rl = r - bk * RPB;
            int pos = atomicAdd(&cur[bk], 1);
            if (pos < ((bk + 1) << CAP_SHIFT))  // slot-overflow guard
                eb1[pos] = make_int2((cols[e] & 0x1FFFF) | (rl << 17), __float_as_int(vals[e]));
        }
    }
}

// ---------------------------------------------------------------- fine scatter + off2 writer
// off2[row] = (start, len) into slotted eb2.
__global__ __launch_bounds__(1024) void fine_scatter_kernel(const int* __restrict__ gcnt,
                                                            const int2* __restrict__ eb1,
                                                            int2* __restrict__ eb2,
                                                            int2* __restrict__ off2,
                                                            int nN) {
    __shared__ int hist[RPB];
    __shared__ int sc[RPB];
    __shared__ int cur[RPB];
    const int b = blockIdx.x;
    const int row0 = b * RPB;
    const int nr = min(RPB, nN - row0);
    const int t = threadIdx.x;
    const int s = b << CAP_SHIFT;
    const int e = s + min(gcnt[b], CAP);

    if (t < RPB) hist[t] = 0;
    __syncthreads();
    for (int i = s + t; i < e; i += 1024)
        atomicAdd(&hist[((unsigned)eb1[i].x) >> 17], 1);
    __syncthreads();

    int myc = (t < RPB) ? hist[t] : 0;
    if (t < RPB) sc[t] = myc;
    __syncthreads();
    for (int d = 1; d < RPB; d <<= 1) {
        int add = (t < RPB && t >= d) ? sc[t - d] : 0;
        __syncthreads();
        if (t < RPB) sc[t] += add;
        __syncthreads();
    }
    if (t < RPB) {
        int excl = s + sc[t] - myc;
        cur[t] = excl;
        if (t < nr) off2[row0 + t] = make_int2(excl, myc);
    }
    __syncthreads();

    for (int i = s + t; i < e; i += 1024) {
        int2 ed = eb1[i];
        unsigned x = (unsigned)ed.x;
        int pos = atomicAdd(&cur[x >> 17], 1);
        eb2[pos] = make_int2((int)(x & 0x1FFFF), ed.y);
    }
}

// ---------------------------------------------------------------- FUSED spmm128 + matvec
// Grid-stride wave-per-row (2048 blocks: w2s loaded once per block, ~12 rows
// per wave amortize the fill and the Poisson tail). Gather: lane =
// (edge-subgroup g = lane>>4, feature-group fg = lane&15); one dwordx4 load
// covers 4 edges' rows. shfl_xor(16,32) combines subgroups; bias+relu; pack
// to per-wave LDS (plain h2t stores); per-row matvec by W2.
__global__ __launch_bounds__(256) void spmm_fused_kernel(const int2* __restrict__ off2,
                                                         const int2* __restrict__ eb,
                                                         const __half* __restrict__ Y,
                                                         const float* __restrict__ b1,
                                                         const h2t* __restrict__ pk,
                                                         __half* __restrict__ Y2, int nN) {
    __shared__ h2t w2s[64 * 64];  // w2s[kk*64+c] = (W2[2kk][c], W2[2kk+1][c])
    __shared__ h2t hs[4][64];     // per-wave relu'd H1 row, packed pairs
    const int t = threadIdx.x;
#pragma unroll
    for (int i = 0; i < 16; ++i) w2s[i * 256 + t] = pk[i * 256 + t];
    __syncthreads();

    const int wv = t >> 6;
    const int lane = t & 63;
    const int fg = lane & 15;  // feature group: 8 halfs at fg*8
    const int g = lane >> 4;   // edge subgroup 0..3
    const int gw = blockIdx.x * 4 + wv;
    const int nw = gridDim.x * 4;

    for (int row = gw; row < nN; row += nw) {
        float acc[8];
#pragma unroll
        for (int p = 0; p < 8; ++p) acc[p] = 0.f;

        int2 se = off2[row];
        int s = se.x;
        int e1 = s + se.y;
        for (int base = s; base < e1; base += 64) {
            int n = min(64, e1 - base);
            int2 my = (lane < n) ? eb[base + lane] : make_int2(0, 0);
            for (int j = 0; j < n; j += 8) {
                int i0 = j + g;
                int i1 = j + 4 + g;
                // clamp invalid subgroup indices onto edge j (same cache
                // lines, valid source lane); contribution zeroed via val.
                int s0 = (i0 < n) ? i0 : j;
                int s1 = (i1 < n) ? i1 : j;
                // UNCONDITIONAL shuffles (full EXEC); mask results after.
                int c0 = __shfl(my.x, s0);
                int c1 = __shfl(my.x, s1);
                float v0 = __int_as_float(__shfl(my.y, s0));
                float v1 = __int_as_float(__shfl(my.y, s1));
                if (i0 >= n) v0 = 0.f;
                if (i1 >= n) v1 = 0.f;
                half8 y0 = *(const half8*)(Y + ((size_t)c0 << 7) + (fg << 3));
                half8 y1 = *(const half8*)(Y + ((size_t)c1 << 7) + (fg << 3));
#pragma unroll
                for (int p = 0; p < 8; ++p) acc[p] = fmaf(v0, (float)y0[p], acc[p]);
#pragma unroll
                for (int p = 0; p < 8; ++p) acc[p] = fmaf(v1, (float)y1[p], acc[p]);
            }
        }
        // combine the 4 edge-subgroups (lanes differ in bits 4,5 only)
#pragma unroll
        for (int p = 0; p < 8; ++p) acc[p] += __shfl_xor(acc[p], 16);
#pragma unroll
        for (int p = 0; p < 8; ++p) acc[p] += __shfl_xor(acc[p], 32);

        // bias + relu + pack into per-wave LDS. PLAIN element-type (h2t)
        // stores only (barrier-less wave-synchronous handoff).
        if (g == 0) {
            floatx4 ba = *(const floatx4*)(b1 + fg * 8);
            floatx4 bb = *(const floatx4*)(b1 + fg * 8 + 4);
            float f[8];
#pragma unroll
            for (int p = 0; p < 4; ++p) f[p] = fmaxf(acc[p] + ba[p], 0.f);
#pragma unroll
            for (int p = 0; p < 4; ++p) f[4 + p] = fmaxf(acc[4 + p] + bb[p], 0.f);
#pragma unroll
            for (int p = 0; p < 4; ++p) {
                h2t pr;
                pr[0] = (_Float16)f[2 * p];
                pr[1] = (_Float16)f[2 * p + 1];
                hs[wv][fg * 4 + p] = pr;  // hs[wv][i] = features (2i, 2i+1)
            }
        }
        __builtin_amdgcn_sched_barrier(0);  // pin handoff order

        // matvec: o = sum_kk dot2(hs[kk], W2pair[kk][lane])
        // (same-wave DS ordering: no barrier needed)
        float o = 0.f;
#pragma unroll 8
        for (int kk = 0; kk < 64; ++kk) {
            h2t a = hs[wv][kk];           // LDS broadcast (free)
            h2t b = w2s[kk * 64 + lane];  // 2-way bank aliasing (free)
#if __has_builtin(__builtin_amdgcn_fdot2)
            o = __builtin_amdgcn_fdot2(a, b, o, false);
#else
            o = fmaf((float)a[0], (float)b[0], o);
            o = fmaf((float)a[1], (float)b[1], o);
#endif
        }
        Y2[(size_t)row * 64 + lane] = __float2half_rn(o);
    }
}

// ---------------------------------------------------------------- spmm F=64 (final layer)
// Grid-stride wave-per-row, 8-lanes-per-edge dwordx4 gather (one load = 8
// edges' 128B rows); acc[8]; shfl_xor(8,16,32) combines subgroups; lanes
// 0..7 write 256B coalesced fp32.
__global__ __launch_bounds__(256) void spmm_csr64_kernel(const int2* __restrict__ off2,
                                                         const int2* __restrict__ eb,
                                                         const __half* __restrict__ Y,
                                                         const float* __restrict__ bias,
                                                         float* __restrict__ out, int nN) {
    const int lane = threadIdx.x & 63;
    const int fg = lane & 7;  // 8 features at fg*8
    const int g = lane >> 3;  // edge subgroup 0..7
    const int gw = blockIdx.x * 4 + (threadIdx.x >> 6);
    const int nw = gridDim.x * 4;

    for (int row = gw; row < nN; row += nw) {
        float acc[8];
#pragma unroll
        for (int p = 0; p < 8; ++p) acc[p] = 0.f;

        int2 se = off2[row];
        int s = se.x;
        int e1 = s + se.y;
        for (int base = s; base < e1; base += 64) {
            int n = min(64, e1 - base);
            int2 my = (lane < n) ? eb[base + lane] : make_int2(0, 0);
            for (int j = 0; j < n; j += 16) {
                int i0 = j + g;
                int i1 = j + 8 + g;
                int s0 = (i0 < n) ? i0 : j;
                int s1 = (i1 < n) ? i1 : j;
                int c0 = __shfl(my.x, s0);
                int c1 = __shfl(my.x, s1);
                float v0 = __int_as_float(__shfl(my.y, s0));
                float v1 = __int_as_float(__shfl(my.y, s1));
                if (i0 >= n) v0 = 0.f;
                if (i1 >= n) v1 = 0.f;
                half8 y0 = *(const half8*)(Y + ((size_t)c0 << 6) + (fg << 3));
                half8 y1 = *(const half8*)(Y + ((size_t)c1 << 6) + (fg << 3));
#pragma unroll
                for (int p = 0; p < 8; ++p) acc[p] = fmaf(v0, (float)y0[p], acc[p]);
#pragma unroll
                for (int p = 0; p < 8; ++p) acc[p] = fmaf(v1, (float)y1[p], acc[p]);
            }
        }
        // combine the 8 edge-subgroups (lanes differ in bits 3,4,5 only)
#pragma unroll
        for (int p = 0; p < 8; ++p) acc[p] += __shfl_xor(acc[p], 8);
#pragma unroll
        for (int p = 0; p < 8; ++p) acc[p] += __shfl_xor(acc[p], 16);
#pragma unroll
        for (int p = 0; p < 8; ++p) acc[p] += __shfl_xor(acc[p], 32);

        if (g == 0) {
            floatx4 ba = *(const floatx4*)(bias + fg * 8);
            floatx4 bb = *(const floatx4*)(bias + fg * 8 + 4);
            floatx4 o0, o1;
#pragma unroll
            for (int p = 0; p < 4; ++p) o0[p] = acc[p] + ba[p];
#pragma unroll
            for (int p = 0; p < 4; ++p) o1[p] = acc[4 + p] + bb[p];
            float* op = out + (size_t)row * 64 + fg * 8;
            *(floatx4*)op = o0;
            *(floatx4*)(op + 4) = o1;
        }
    }
}

// ---------------------------------------------------------------- fallback atomic path
__global__ __launch_bounds__(256) void init_bias_kernel(float* __restrict__ out,
                                                        const float* __restrict__ bias,
                                                        int fmask, size_t total) {
    size_t i = (size_t)blockIdx.x * 256 + threadIdx.x;
    if (i < total) out[i] = bias[i & fmask];
}

template <int F>
__global__ __launch_bounds__(256) void spmm_atomic_kernel(const int* __restrict__ rows,
                                                          const int* __restrict__ cols,
                                                          const float* __restrict__ vals,
                                                          const __half* __restrict__ Y,
                                                          float* __restrict__ out, int nE) {
    int e = blockIdx.x * 4 + (threadIdx.x >> 6);
    if (e >= nE) return;
    int lane = threadIdx.x & 63;
    int r = rows[e];
    int c = cols[e];
    float v = vals[e];
    if (F == 128) {
        float2 y = __half22float2(*((const __half2*)(Y + (size_t)c * 128) + lane));
        float* op = out + (size_t)r * 128 + lane * 2;
        unsafeAtomicAdd(op, v * y.x);
        unsafeAtomicAdd(op + 1, v * y.y);
    } else {
        float y = __half2float(Y[(size_t)c * F + lane]);
        unsafeAtomicAdd(out + (size_t)r * F + lane, v * y);
    }
}

// ---------------------------------------------------------------- MFMA fp16 GEMM
// C[nrows,NN] (fp16) = (RELU_IN ? relu(A) : A)[nrows,KK] (fp32) @ B[KK,NN]
template <int NN, int KK, bool RELU_IN>
__global__ __launch_bounds__(256) void gemm_mfma_kernel(const float* __restrict__ A,
                                                        const __half* __restrict__ BT,
                                                        __half* __restrict__ C, int nrows) {
    constexpr int MT = 64, KT = 64, KP = KT + 8;
    __shared__ __half As[MT * KP];
    __shared__ __half Bs[NN * KP];
    const int tid = threadIdx.x;
    const int wid = tid >> 6, lane = tid & 63;
    const int row0 = blockIdx.x * MT;
    const int wr = wid & 1, wc = wid >> 1;
    constexpr int WCT = NN / 32;
    const int lrow = lane & 15, q = lane >> 4;

    floatx4 acc[2][WCT];
#pragma unroll
    for (int rt = 0; rt < 2; ++rt)
#pragma unroll
        for (int ct = 0; ct < WCT; ++ct)
#pragma unroll
            for (int i = 0; i < 4; ++i) acc[rt][ct][i] = 0.f;

    for (int kt = 0; kt < KK; kt += KT) {
#pragma unroll
        for (int it = 0; it < MT * KT / 4 / 256; ++it) {
            int i4 = it * 256 + tid;
            int m = i4 >> 4;
            int kk = (i4 & 15) << 2;
            int gr = row0 + m;
            float4 v = make_float4(0.f, 0.f, 0.f, 0.f);
            if (gr < nrows) v = *(const float4*)(A + (size_t)gr * KK + kt + kk);
            if (RELU_IN) {
                v.x = fmaxf(v.x, 0.f); v.y = fmaxf(v.y, 0.f);
                v.z = fmaxf(v.z, 0.f); v.w = fmaxf(v.w, 0.f);
            }
            __half h0 = __float2half_rn(v.x), h1 = __float2half_rn(v.y);
            __half h2 = __float2half_rn(v.z), h3 = __float2half_rn(v.w);
            ushort4 u = make_ushort4(*(unsigned short*)&h0, *(unsigned short*)&h1,
                                     *(unsigned short*)&h2, *(unsigned short*)&h3);
            *(ushort4*)(As + m * KP + kk) = u;
        }
#pragma unroll
        for (int it = 0; it < NN * KT / 4 / 256; ++it) {
            int i4 = it * 256 + tid;
            int n = i4 >> 4;
            int kk = (i4 & 15) << 2;
            *(ushort4*)(Bs + n * KP + kk) =
                *(const ushort4*)(BT + (size_t)n * KK + kt + kk);
        }
        __syncthreads();

#pragma unroll
        for (int ks = 0; ks < KT; ks += 32) {
            half8 a0 = *(half8*)(As + (wr * 32 + lrow) * KP + ks + q * 8);
            half8 a1 = *(half8*)(As + (wr * 32 + 16 + lrow) * KP + ks + q * 8);
#pragma unroll
            for (int ct = 0; ct < WCT; ++ct) {
                half8 b = *(half8*)(Bs + (wc * (NN / 2) + ct * 16 + lrow) * KP + ks + q * 8);
                acc[0][ct] = __builtin_amdgcn_mfma_f32_16x16x32_f16(a0, b, acc[0][ct], 0, 0, 0);
                acc[1][ct] = __builtin_amdgcn_mfma_f32_16x16x32_f16(a1, b, acc[1][ct], 0, 0, 0);
            }
        }
        __syncthreads();
    }

#pragma unroll
    for (int rt = 0; rt < 2; ++rt)
#pragma unroll
        for (int ct = 0; ct < WCT; ++ct)
#pragma unroll
            for (int r = 0; r < 4; ++r) {
                int gr = row0 + wr * 32 + rt * 16 + q * 4 + r;
                if (gr < nrows)
                    C[(size_t)gr * NN + wc * (NN / 2) + ct * 16 + lrow] =
                        __float2half_rn(acc[rt][ct][r]);
            }
}

extern "C" void kernel_launch(void* const* d_in, const int* in_sizes, int n_in,
                              void* d_out, int out_size, void* d_ws, size_t ws_size,
                              hipStream_t stream) {
    const float* x    = (const float*)d_in[0];
    const int*   rows = (const int*)d_in[1];
    const int*   cols = (const int*)d_in[2];
    const float* vals = (const float*)d_in[3];
    const float* W1   = (const float*)d_in[4];
    const float* b1   = (const float*)d_in[5];
    const float* W2   = (const float*)d_in[6];
    const float* b2   = (const float*)d_in[7];
    float* out = (float*)d_out;

    const int nN = in_sizes[0] / 256;  // 100000
    const int nE = in_sizes[1];        // 3200000
    const int nB = (nN + RPB - 1) / RPB;

    const int mblocks  = (nN + 63) / 64;
    const int pblocks  = (nE + PCHUNK - 1) / PCHUNK;
    const int sblocks  = min(2048, (nN + 3) / 4);  // grid-stride spmm
    const int eblocks4 = (nE + 3) / 4;

    // ---- fast-path ws layout (compact; no fp32 H1) ----
    char* w = (char*)d_ws;
    __half* Y1h  = (__half*)w;  w += (size_t)nN * 128 * 2;
    __half* Y2h  = (__half*)w;  w += (size_t)nN * 64 * 2;
    __half* W1T  = (__half*)w;  w += (size_t)256 * 128 * 2;
    h2t*    pk   = (h2t*)w;     w += (size_t)4096 * 4;
    int2*   off2 = (int2*)w;    w += (size_t)nN * 8;
    int*    gcnt = (int*)w;     w += (size_t)NB_MAX * 4;
    int2*   eb1  = (int2*)w;    w += ((size_t)nB << CAP_SHIFT) * 8;
    int2*   eb2  = (int2*)w;    w += ((size_t)nB << CAP_SHIFT) * 8;
    size_t need = (size_t)(w - (char*)d_ws);

    // slot safety: mean bucket load + ~8.5 sigma must fit in CAP
    const bool slots_ok = (nE / nB) <= (CAP - 1050);

    if (ws_size >= need && nN <= (1 << 17) && nB <= NB_MAX && slots_ok) {
        // ---- fast path (6 dispatches) ----
        prep_weights_kernel<<<(256 * 128 + 4096 + NB_MAX + 255) / 256, 256, 0, stream>>>(
            W1, W2, W1T, pk, gcnt);
        gemm_mfma_kernel<128, 256, false><<<mblocks, 256, 0, stream>>>(x, W1T, Y1h, nN);

        partition_kernel<<<pblocks, 256, 0, stream>>>(rows, cols, vals, gcnt, eb1, nE, nB);
        fine_scatter_kernel<<<nB, 1024, 0, stream>>>(gcnt, eb1, eb2, off2, nN);

        // Y2 = fp16(relu(b1 + spmm(Y1)) @ W2)   [fused]
        spmm_fused_kernel<<<sblocks, 256, 0, stream>>>(off2, eb2, Y1h, b1, pk, Y2h, nN);
        // out = b2 + spmm(Y2)
        spmm_csr64_kernel<<<sblocks, 256, 0, stream>>>(off2, eb2, Y2h, b2, out, nN);
    } else {
        // ---- fallback: atomic path (own ws layout) ----
        char* v = (char*)d_ws;
        __half* fY1h = (__half*)v;  v += (size_t)nN * 128 * 2;
        float*  fH1  = (float*)v;   v += (size_t)nN * 128 * 4;
        __half* fW1T = (__half*)v;  v += (size_t)256 * 128 * 2;
        __half* fW2T = (__half*)v;  v += (size_t)128 * 64 * 2;

        transpose_w_kernel<<<(256 * 128 + 255) / 256, 256, 0, stream>>>(W1, fW1T, 256, 128);
        transpose_w_kernel<<<(128 * 64 + 255) / 256, 256, 0, stream>>>(W2, fW2T, 128, 64);
        gemm_mfma_kernel<128, 256, false><<<mblocks, 256, 0, stream>>>(x, fW1T, fY1h, nN);
        size_t totH1 = (size_t)nN * 128;
        init_bias_kernel<<<(int)((totH1 + 255) / 256), 256, 0, stream>>>(fH1, b1, 127, totH1);
        spmm_atomic_kernel<128><<<eblocks4, 256, 0, stream>>>(rows, cols, vals, fY1h, fH1, nE);
        gemm_mfma_kernel<64, 128, true><<<mblocks, 256, 0, stream>>>(fH1, fW2T, fY1h, nN);
        size_t totOut = (size_t)nN * 64;
        init_bias_kernel<<<(int)((totOut + 255) / 256), 256, 0, stream>>>(out, b2, 63, totOut);
        spmm_atomic_kernel<64><<<eblocks4, 256, 0, stream>>>(rows, cols, vals, fY1h, out, nE);
    }
}

// Round 6
// 450.374 us; speedup vs baseline: 1.1553x; 1.0282x over previous
//
#include <hip/hip_runtime.h>
#include <hip/hip_fp16.h>

// GCN encoder:
//   Y1 = fp16(x @ W1)                   MFMA f16 (fp32 acc), [N,256]x[256,128]
//   Y2 = fp16(relu(b1 + spmm(Y1)) @ W2) spmm128 w/ FUSED matvec epilogue
//   out = b2 + spmm(Y2)                 (wave-per-row, F=64)
// spmm(x)@W == spmm(x@W) (linearity); biases folded into spmm accumulators.
//
// Pipeline (fast path, 5 dispatches):
//   prep (W1T cast, pk pack, gcnt zero)
//   gemm_part  = gemm1 MERGED WITH partition (independent: block-range split,
//                partition blocks first; dynamic LDS = max of branches)
//   fine_scatter -> spmm_fused -> spmm_csr64
//
// Round-3 lesson: spmm stays high-occupancy/low-LDS (TLP hides gather latency).
// Round-5 lesson: fp32 VALU GEMM had 1.28e7 LDS bank conflicts -> MFMA fp16.
// Round-6 lesson: millions of random global atomics write ~32B/op to HBM.
// Round-7 lesson: scatter run length = PCHUNK/nB; keep runs fat.
// Round-8/12 lesson: spmm gathers run at the per-CU random-gather ceiling
// (~12 B/cy/CU; 43% L2 miss at fp16 Y1 since 25.6MB >> 4MB/XCD L2).
// Round-14 lesson: grid-stride + w2s-amortization did NOT move spmm_fused
// (113us both ways) -- it is ceiling-bound, not overhead-bound. Remaining
// recoverable time is in the serial chain around it -> merge independent
// gemm1 & partition into one dispatch.
// Round-11 lesson: __shfl under a per-lane predicate exec-masks ds_bpermute;
// issue shuffles with full EXEC, mask the RESULT.
// Round-10 lesson: barrier-less wave-synchronous LDS handoff requires plain
// element-type stores (type-punned wide stores get TBAA-reordered).

#define RPB 480        // rows per coarse bucket (rowlocal fits 9 bits)
#define NB_MAX 1024    // max buckets
#define PCHUNK 8192    // edges per partition block (256 thr x 32)
#define EPT 32         // edges per thread in partition
#define CAP_SHIFT 14   // 16384-edge slot per bucket (mean 15311 @ nE=3.2M)
#define CAP (1 << CAP_SHIFT)

typedef _Float16 half8 __attribute__((ext_vector_type(8)));
typedef _Float16 h2t __attribute__((ext_vector_type(2)));
typedef float floatx4 __attribute__((ext_vector_type(4)));

// ---------------------------------------------------------------- weight prep (fast path)
// W1T[n][k] = fp16(W1[k][n]); pk[kk*64+c] = (W2[2kk][c], W2[2kk+1][c]) fp16
// tail threads: zero gcnt (partition's slot cursors)
__global__ __launch_bounds__(256) void prep_weights_kernel(const float* __restrict__ W1,
                                                           const float* __restrict__ W2,
                                                           __half* __restrict__ W1T,
                                                           h2t* __restrict__ pk,
                                                           int* __restrict__ gcnt) {
    int i = blockIdx.x * 256 + threadIdx.x;
    if (i < 256 * 128) {
        int k = i >> 7, n = i & 127;
        W1T[n * 256 + k] = __float2half_rn(W1[i]);
    } else if (i < 256 * 128 + 4096) {
        int j = i - 256 * 128;
        int kk = j >> 6, c = j & 63;
        h2t v;
        v[0] = (_Float16)W2[(2 * kk) * 64 + c];
        v[1] = (_Float16)W2[(2 * kk + 1) * 64 + c];
        pk[j] = v;
    } else {
        int j = i - (256 * 128 + 4096);
        if (j < NB_MAX) gcnt[j] = 0;
    }
}

// ---------------------------------------------------------------- W transpose+cast (fallback)
__global__ __launch_bounds__(256) void transpose_w_kernel(const float* __restrict__ W,
                                                          __half* __restrict__ WT,
                                                          int K, int N) {
    int i = blockIdx.x * 256 + threadIdx.x;
    if (i < K * N) {
        int k = i / N, n = i % N;
        WT[n * K + k] = __float2half_rn(W[i]);
    }
}

// ---------------------------------------------------------------- MERGED gemm1 || partition
// blocks [0, pblocks): coarse multisplit partition of edges into per-bucket
//   16K slots (payload: col | rowlocal<<17, val; gcnt[b] = cursor/count).
// blocks [pblocks, ...): MFMA fp16 gemm Y1 = fp16(x @ W1), MT=64, NN=128,
//   KK=256 (specialized copy of gemm_mfma_kernel<128,256,false>).
// Dynamic LDS = max(2*NB_MAX*4, (64+128)*72*2) = 27648 B.
__global__ __launch_bounds__(256) void gemm_part_kernel(
    const float* __restrict__ A, const __half* __restrict__ BT,
    __half* __restrict__ C, int nrows,
    const int* __restrict__ rows, const int* __restrict__ cols,
    const float* __restrict__ vals, int* __restrict__ gcnt,
    int2* __restrict__ eb1, int nE, int nB, int pblocks) {
    extern __shared__ char smem[];
    const int t = threadIdx.x;

    if ((int)blockIdx.x < pblocks) {
        // ---------------- partition branch ----------------
        int* hist = (int*)smem;
        int* cur = hist + NB_MAX;
        const int c0 = blockIdx.x * PCHUNK;
        for (int b = t; b < nB; b += 256) hist[b] = 0;
        __syncthreads();
        int myr[EPT];
#pragma unroll
        for (int j = 0; j < EPT; ++j) {
            int e = c0 + t + 256 * j;
            int r = (e < nE) ? rows[e] : -1;
            myr[j] = r;
            if (r >= 0) atomicAdd(&hist[r / RPB], 1);
        }
        __syncthreads();
        for (int b = t; b < nB; b += 256) {
            int c = hist[b];
            cur[b] = c ? (b << CAP_SHIFT) + atomicAdd(&gcnt[b], c) : 0;
        }
        __syncthreads();
#pragma unroll
        for (int j = 0; j < EPT; ++j) {
            int r = myr[j];
            if (r >= 0) {
                int e = c0 + t + 256 * j;
                int bk = r / RPB;
                int rl = r - bk * RPB;
                int pos = atomicAdd(&cur[bk], 1);
                if (pos < ((bk + 1) << CAP_SHIFT))  // slot-overflow guard
                    eb1[pos] = make_int2((cols[e] & 0x1FFFF) | (rl << 17),
                                         __float_as_int(vals[e]));
            }
        }
    } else {
        // ---------------- gemm branch (NN=128, KK=256, no relu) ----------------
        constexpr int MT = 64, KT = 64, KP = KT + 8, NN = 128, KK = 256;
        constexpr int WCT = NN / 32;
        __half* As = (__half*)smem;        // MT*KP
        __half* Bs = As + MT * KP;         // NN*KP
        const int wid = t >> 6, lane = t & 63;
        const int row0 = ((int)blockIdx.x - pblocks) * MT;
        const int wr = wid & 1, wc = wid >> 1;
        const int lrow = lane & 15, q = lane >> 4;

        floatx4 acc[2][WCT];
#pragma unroll
        for (int rt = 0; rt < 2; ++rt)
#pragma unroll
            for (int ct = 0; ct < WCT; ++ct)
#pragma unroll
                for (int i = 0; i < 4; ++i) acc[rt][ct][i] = 0.f;

        for (int kt = 0; kt < KK; kt += KT) {
#pragma unroll
            for (int it = 0; it < MT * KT / 4 / 256; ++it) {
                int i4 = it * 256 + t;
                int m = i4 >> 4;
                int kk = (i4 & 15) << 2;
                int gr = row0 + m;
                float4 v = make_float4(0.f, 0.f, 0.f, 0.f);
                if (gr < nrows) v = *(const float4*)(A + (size_t)gr * KK + kt + kk);
                __half h0 = __float2half_rn(v.x), h1 = __float2half_rn(v.y);
                __half h2 = __float2half_rn(v.z), h3 = __float2half_rn(v.w);
                ushort4 u = make_ushort4(*(unsigned short*)&h0, *(unsigned short*)&h1,
                                         *(unsigned short*)&h2, *(unsigned short*)&h3);
                *(ushort4*)(As + m * KP + kk) = u;
            }
#pragma unroll
            for (int it = 0; it < NN * KT / 4 / 256; ++it) {
                int i4 = it * 256 + t;
                int n = i4 >> 4;
                int kk = (i4 & 15) << 2;
                *(ushort4*)(Bs + n * KP + kk) =
                    *(const ushort4*)(BT + (size_t)n * KK + kt + kk);
            }
            __syncthreads();

#pragma unroll
            for (int ks = 0; ks < KT; ks += 32) {
                half8 a0 = *(half8*)(As + (wr * 32 + lrow) * KP + ks + q * 8);
                half8 a1 = *(half8*)(As + (wr * 32 + 16 + lrow) * KP + ks + q * 8);
#pragma unroll
                for (int ct = 0; ct < WCT; ++ct) {
                    half8 b = *(half8*)(Bs + (wc * (NN / 2) + ct * 16 + lrow) * KP + ks + q * 8);
                    acc[0][ct] = __builtin_amdgcn_mfma_f32_16x16x32_f16(a0, b, acc[0][ct], 0, 0, 0);
                    acc[1][ct] = __builtin_amdgcn_mfma_f32_16x16x32_f16(a1, b, acc[1][ct], 0, 0, 0);
                }
            }
            __syncthreads();
        }

#pragma unroll
        for (int rt = 0; rt < 2; ++rt)
#pragma unroll
            for (int ct = 0; ct < WCT; ++ct)
#pragma unroll
                for (int r = 0; r < 4; ++r) {
                    int gr = row0 + wr * 32 + rt * 16 + q * 4 + r;
                    if (gr < nrows)
                        C[(size_t)gr * NN + wc * (NN / 2) + ct * 16 + lrow] =
                            __float2half_rn(acc[rt][ct][r]);
                }
    }
}

// ---------------------------------------------------------------- fine scatter + off2 writer
// off2[row] = (start, len) into slotted eb2.
__global__ __launch_bounds__(1024) void fine_scatter_kernel(const int* __restrict__ gcnt,
                                                            const int2* __restrict__ eb1,
                                                            int2* __restrict__ eb2,
                                                            int2* __restrict__ off2,
                                                            int nN) {
    __shared__ int hist[RPB];
    __shared__ int sc[RPB];
    __shared__ int cur[RPB];
    const int b = blockIdx.x;
    const int row0 = b * RPB;
    const int nr = min(RPB, nN - row0);
    const int t = threadIdx.x;
    const int s = b << CAP_SHIFT;
    const int e = s + min(gcnt[b], CAP);

    if (t < RPB) hist[t] = 0;
    __syncthreads();
    for (int i = s + t; i < e; i += 1024)
        atomicAdd(&hist[((unsigned)eb1[i].x) >> 17], 1);
    __syncthreads();

    int myc = (t < RPB) ? hist[t] : 0;
    if (t < RPB) sc[t] = myc;
    __syncthreads();
    for (int d = 1; d < RPB; d <<= 1) {
        int add = (t < RPB && t >= d) ? sc[t - d] : 0;
        __syncthreads();
        if (t < RPB) sc[t] += add;
        __syncthreads();
    }
    if (t < RPB) {
        int excl = s + sc[t] - myc;
        cur[t] = excl;
        if (t < nr) off2[row0 + t] = make_int2(excl, myc);
    }
    __syncthreads();

    for (int i = s + t; i < e; i += 1024) {
        int2 ed = eb1[i];
        unsigned x = (unsigned)ed.x;
        int pos = atomicAdd(&cur[x >> 17], 1);
        eb2[pos] = make_int2((int)(x & 0x1FFFF), ed.y);
    }
}

// ---------------------------------------------------------------- FUSED spmm128 + matvec
// Grid-stride wave-per-row. Gather: lane = (edge-subgroup g = lane>>4,
// feature-group fg = lane&15); one dwordx4 load covers 4 edges' rows.
// shfl_xor(16,32) combines subgroups; bias+relu; pack to per-wave LDS
// (plain h2t stores); per-row matvec by W2.
__global__ __launch_bounds__(256) void spmm_fused_kernel(const int2* __restrict__ off2,
                                                         const int2* __restrict__ eb,
                                                         const __half* __restrict__ Y,
                                                         const float* __restrict__ b1,
                                                         const h2t* __restrict__ pk,
                                                         __half* __restrict__ Y2, int nN) {
    __shared__ h2t w2s[64 * 64];  // w2s[kk*64+c] = (W2[2kk][c], W2[2kk+1][c])
    __shared__ h2t hs[4][64];     // per-wave relu'd H1 row, packed pairs
    const int t = threadIdx.x;
#pragma unroll
    for (int i = 0; i < 16; ++i) w2s[i * 256 + t] = pk[i * 256 + t];
    __syncthreads();

    const int wv = t >> 6;
    const int lane = t & 63;
    const int fg = lane & 15;  // feature group: 8 halfs at fg*8
    const int g = lane >> 4;   // edge subgroup 0..3
    const int gw = blockIdx.x * 4 + wv;
    const int nw = gridDim.x * 4;

    for (int row = gw; row < nN; row += nw) {
        float acc[8];
#pragma unroll
        for (int p = 0; p < 8; ++p) acc[p] = 0.f;

        int2 se = off2[row];
        int s = se.x;
        int e1 = s + se.y;
        for (int base = s; base < e1; base += 64) {
            int n = min(64, e1 - base);
            int2 my = (lane < n) ? eb[base + lane] : make_int2(0, 0);
            for (int j = 0; j < n; j += 8) {
                int i0 = j + g;
                int i1 = j + 4 + g;
                // clamp invalid subgroup indices onto edge j (same cache
                // lines, valid source lane); contribution zeroed via val.
                int s0 = (i0 < n) ? i0 : j;
                int s1 = (i1 < n) ? i1 : j;
                // UNCONDITIONAL shuffles (full EXEC); mask results after.
                int c0 = __shfl(my.x, s0);
                int c1 = __shfl(my.x, s1);
                float v0 = __int_as_float(__shfl(my.y, s0));
                float v1 = __int_as_float(__shfl(my.y, s1));
                if (i0 >= n) v0 = 0.f;
                if (i1 >= n) v1 = 0.f;
                half8 y0 = *(const half8*)(Y + ((size_t)c0 << 7) + (fg << 3));
                half8 y1 = *(const half8*)(Y + ((size_t)c1 << 7) + (fg << 3));
#pragma unroll
                for (int p = 0; p < 8; ++p) acc[p] = fmaf(v0, (float)y0[p], acc[p]);
#pragma unroll
                for (int p = 0; p < 8; ++p) acc[p] = fmaf(v1, (float)y1[p], acc[p]);
            }
        }
        // combine the 4 edge-subgroups (lanes differ in bits 4,5 only)
#pragma unroll
        for (int p = 0; p < 8; ++p) acc[p] += __shfl_xor(acc[p], 16);
#pragma unroll
        for (int p = 0; p < 8; ++p) acc[p] += __shfl_xor(acc[p], 32);

        // bias + relu + pack into per-wave LDS. PLAIN element-type (h2t)
        // stores only (barrier-less wave-synchronous handoff).
        if (g == 0) {
            floatx4 ba = *(const floatx4*)(b1 + fg * 8);
            floatx4 bb = *(const floatx4*)(b1 + fg * 8 + 4);
            float f[8];
#pragma unroll
            for (int p = 0; p < 4; ++p) f[p] = fmaxf(acc[p] + ba[p], 0.f);
#pragma unroll
            for (int p = 0; p < 4; ++p) f[4 + p] = fmaxf(acc[4 + p] + bb[p], 0.f);
#pragma unroll
            for (int p = 0; p < 4; ++p) {
                h2t pr;
                pr[0] = (_Float16)f[2 * p];
                pr[1] = (_Float16)f[2 * p + 1];
                hs[wv][fg * 4 + p] = pr;  // hs[wv][i] = features (2i, 2i+1)
            }
        }
        __builtin_amdgcn_sched_barrier(0);  // pin handoff order

        // matvec: o = sum_kk dot2(hs[kk], W2pair[kk][lane])
        // (same-wave DS ordering: no barrier needed)
        float o = 0.f;
#pragma unroll 8
        for (int kk = 0; kk < 64; ++kk) {
            h2t a = hs[wv][kk];           // LDS broadcast (free)
            h2t b = w2s[kk * 64 + lane];  // 2-way bank aliasing (free)
#if __has_builtin(__builtin_amdgcn_fdot2)
            o = __builtin_amdgcn_fdot2(a, b, o, false);
#else
            o = fmaf((float)a[0], (float)b[0], o);
            o = fmaf((float)a[1], (float)b[1], o);
#endif
        }
        Y2[(size_t)row * 64 + lane] = __float2half_rn(o);
    }
}

// ---------------------------------------------------------------- spmm F=64 (final layer)
// Grid-stride wave-per-row, 8-lanes-per-edge dwordx4 gather (one load = 8
// edges' 128B rows); acc[8]; shfl_xor(8,16,32) combines subgroups; lanes
// 0..7 write 256B coalesced fp32.
__global__ __launch_bounds__(256) void spmm_csr64_kernel(const int2* __restrict__ off2,
                                                         const int2* __restrict__ eb,
                                                         const __half* __restrict__ Y,
                                                         const float* __restrict__ bias,
                                                         float* __restrict__ out, int nN) {
    const int lane = threadIdx.x & 63;
    const int fg = lane & 7;  // 8 features at fg*8
    const int g = lane >> 3;  // edge subgroup 0..7
    const int gw = blockIdx.x * 4 + (threadIdx.x >> 6);
    const int nw = gridDim.x * 4;

    for (int row = gw; row < nN; row += nw) {
        float acc[8];
#pragma unroll
        for (int p = 0; p < 8; ++p) acc[p] = 0.f;

        int2 se = off2[row];
        int s = se.x;
        int e1 = s + se.y;
        for (int base = s; base < e1; base += 64) {
            int n = min(64, e1 - base);
            int2 my = (lane < n) ? eb[base + lane] : make_int2(0, 0);
            for (int j = 0; j < n; j += 16) {
                int i0 = j + g;
                int i1 = j + 8 + g;
                int s0 = (i0 < n) ? i0 : j;
                int s1 = (i1 < n) ? i1 : j;
                int c0 = __shfl(my.x, s0);
                int c1 = __shfl(my.x, s1);
                float v0 = __int_as_float(__shfl(my.y, s0));
                float v1 = __int_as_float(__shfl(my.y, s1));
                if (i0 >= n) v0 = 0.f;
                if (i1 >= n) v1 = 0.f;
                half8 y0 = *(const half8*)(Y + ((size_t)c0 << 6) + (fg << 3));
                half8 y1 = *(const half8*)(Y + ((size_t)c1 << 6) + (fg << 3));
#pragma unroll
                for (int p = 0; p < 8; ++p) acc[p] = fmaf(v0, (float)y0[p], acc[p]);
#pragma unroll
                for (int p = 0; p < 8; ++p) acc[p] = fmaf(v1, (float)y1[p], acc[p]);
            }
        }
        // combine the 8 edge-subgroups (lanes differ in bits 3,4,5 only)
#pragma unroll
        for (int p = 0; p < 8; ++p) acc[p] += __shfl_xor(acc[p], 8);
#pragma unroll
        for (int p = 0; p < 8; ++p) acc[p] += __shfl_xor(acc[p], 16);
#pragma unroll
        for (int p = 0; p < 8; ++p) acc[p] += __shfl_xor(acc[p], 32);

        if (g == 0) {
            floatx4 ba = *(const floatx4*)(bias + fg * 8);
            floatx4 bb = *(const floatx4*)(bias + fg * 8 + 4);
            floatx4 o0, o1;
#pragma unroll
            for (int p = 0; p < 4; ++p) o0[p] = acc[p] + ba[p];
#pragma unroll
            for (int p = 0; p < 4; ++p) o1[p] = acc[4 + p] + bb[p];
            float* op = out + (size_t)row * 64 + fg * 8;
            *(floatx4*)op = o0;
            *(floatx4*)(op + 4) = o1;
        }
    }
}

// ---------------------------------------------------------------- fallback atomic path
__global__ __launch_bounds__(256) void init_bias_kernel(float* __restrict__ out,
                                                        const float* __restrict__ bias,
                                                        int fmask, size_t total) {
    size_t i = (size_t)blockIdx.x * 256 + threadIdx.x;
    if (i < total) out[i] = bias[i & fmask];
}

template <int F>
__global__ __launch_bounds__(256) void spmm_atomic_kernel(const int* __restrict__ rows,
                                                          const int* __restrict__ cols,
                                                          const float* __restrict__ vals,
                                                          const __half* __restrict__ Y,
                                                          float* __restrict__ out, int nE) {
    int e = blockIdx.x * 4 + (threadIdx.x >> 6);
    if (e >= nE) return;
    int lane = threadIdx.x & 63;
    int r = rows[e];
    int c = cols[e];
    float v = vals[e];
    if (F == 128) {
        float2 y = __half22float2(*((const __half2*)(Y + (size_t)c * 128) + lane));
        float* op = out + (size_t)r * 128 + lane * 2;
        unsafeAtomicAdd(op, v * y.x);
        unsafeAtomicAdd(op + 1, v * y.y);
    } else {
        float y = __half2float(Y[(size_t)c * F + lane]);
        unsafeAtomicAdd(out + (size_t)r * F + lane, v * y);
    }
}

// ---------------------------------------------------------------- MFMA fp16 GEMM (fallback)
// C[nrows,NN] (fp16) = (RELU_IN ? relu(A) : A)[nrows,KK] (fp32) @ B[KK,NN]
template <int NN, int KK, bool RELU_IN>
__global__ __launch_bounds__(256) void gemm_mfma_kernel(const float* __restrict__ A,
                                                        const __half* __restrict__ BT,
                                                        __half* __restrict__ C, int nrows) {
    constexpr int MT = 64, KT = 64, KP = KT + 8;
    __shared__ __half As[MT * KP];
    __shared__ __half Bs[NN * KP];
    const int tid = threadIdx.x;
    const int wid = tid >> 6, lane = tid & 63;
    const int row0 = blockIdx.x * MT;
    const int wr = wid & 1, wc = wid >> 1;
    constexpr int WCT = NN / 32;
    const int lrow = lane & 15, q = lane >> 4;

    floatx4 acc[2][WCT];
#pragma unroll
    for (int rt = 0; rt < 2; ++rt)
#pragma unroll
        for (int ct = 0; ct < WCT; ++ct)
#pragma unroll
            for (int i = 0; i < 4; ++i) acc[rt][ct][i] = 0.f;

    for (int kt = 0; kt < KK; kt += KT) {
#pragma unroll
        for (int it = 0; it < MT * KT / 4 / 256; ++it) {
            int i4 = it * 256 + tid;
            int m = i4 >> 4;
            int kk = (i4 & 15) << 2;
            int gr = row0 + m;
            float4 v = make_float4(0.f, 0.f, 0.f, 0.f);
            if (gr < nrows) v = *(const float4*)(A + (size_t)gr * KK + kt + kk);
            if (RELU_IN) {
                v.x = fmaxf(v.x, 0.f); v.y = fmaxf(v.y, 0.f);
                v.z = fmaxf(v.z, 0.f); v.w = fmaxf(v.w, 0.f);
            }
            __half h0 = __float2half_rn(v.x), h1 = __float2half_rn(v.y);
            __half h2 = __float2half_rn(v.z), h3 = __float2half_rn(v.w);
            ushort4 u = make_ushort4(*(unsigned short*)&h0, *(unsigned short*)&h1,
                                     *(unsigned short*)&h2, *(unsigned short*)&h3);
            *(ushort4*)(As + m * KP + kk) = u;
        }
#pragma unroll
        for (int it = 0; it < NN * KT / 4 / 256; ++it) {
            int i4 = it * 256 + tid;
            int n = i4 >> 4;
            int kk = (i4 & 15) << 2;
            *(ushort4*)(Bs + n * KP + kk) =
                *(const ushort4*)(BT + (size_t)n * KK + kt + kk);
        }
        __syncthreads();

#pragma unroll
        for (int ks = 0; ks < KT; ks += 32) {
            half8 a0 = *(half8*)(As + (wr * 32 + lrow) * KP + ks + q * 8);
            half8 a1 = *(half8*)(As + (wr * 32 + 16 + lrow) * KP + ks + q * 8);
#pragma unroll
            for (int ct = 0; ct < WCT; ++ct) {
                half8 b = *(half8*)(Bs + (wc * (NN / 2) + ct * 16 + lrow) * KP + ks + q * 8);
                acc[0][ct] = __builtin_amdgcn_mfma_f32_16x16x32_f16(a0, b, acc[0][ct], 0, 0, 0);
                acc[1][ct] = __builtin_amdgcn_mfma_f32_16x16x32_f16(a1, b, acc[1][ct], 0, 0, 0);
            }
        }
        __syncthreads();
    }

#pragma unroll
    for (int rt = 0; rt < 2; ++rt)
#pragma unroll
        for (int ct = 0; ct < WCT; ++ct)
#pragma unroll
            for (int r = 0; r < 4; ++r) {
                int gr = row0 + wr * 32 + rt * 16 + q * 4 + r;
                if (gr < nrows)
                    C[(size_t)gr * NN + wc * (NN / 2) + ct * 16 + lrow] =
                        __float2half_rn(acc[rt][ct][r]);
            }
}

extern "C" void kernel_launch(void* const* d_in, const int* in_sizes, int n_in,
                              void* d_out, int out_size, void* d_ws, size_t ws_size,
                              hipStream_t stream) {
    const float* x    = (const float*)d_in[0];
    const int*   rows = (const int*)d_in[1];
    const int*   cols = (const int*)d_in[2];
    const float* vals = (const float*)d_in[3];
    const float* W1   = (const float*)d_in[4];
    const float* b1   = (const float*)d_in[5];
    const float* W2   = (const float*)d_in[6];
    const float* b2   = (const float*)d_in[7];
    float* out = (float*)d_out;

    const int nN = in_sizes[0] / 256;  // 100000
    const int nE = in_sizes[1];        // 3200000
    const int nB = (nN + RPB - 1) / RPB;

    const int mblocks  = (nN + 63) / 64;
    const int pblocks  = (nE + PCHUNK - 1) / PCHUNK;
    const int sblocks  = min(2048, (nN + 3) / 4);  // grid-stride spmm
    const int eblocks4 = (nE + 3) / 4;

    // ---- fast-path ws layout (compact; no fp32 H1) ----
    char* w = (char*)d_ws;
    __half* Y1h  = (__half*)w;  w += (size_t)nN * 128 * 2;
    __half* Y2h  = (__half*)w;  w += (size_t)nN * 64 * 2;
    __half* W1T  = (__half*)w;  w += (size_t)256 * 128 * 2;
    h2t*    pk   = (h2t*)w;     w += (size_t)4096 * 4;
    int2*   off2 = (int2*)w;    w += (size_t)nN * 8;
    int*    gcnt = (int*)w;     w += (size_t)NB_MAX * 4;
    int2*   eb1  = (int2*)w;    w += ((size_t)nB << CAP_SHIFT) * 8;
    int2*   eb2  = (int2*)w;    w += ((size_t)nB << CAP_SHIFT) * 8;
    size_t need = (size_t)(w - (char*)d_ws);

    // slot safety: mean bucket load + ~8.5 sigma must fit in CAP
    const bool slots_ok = (nE / nB) <= (CAP - 1050);

    if (ws_size >= need && nN <= (1 << 17) && nB <= NB_MAX && slots_ok) {
        // ---- fast path (5 dispatches) ----
        prep_weights_kernel<<<(256 * 128 + 4096 + NB_MAX + 255) / 256, 256, 0, stream>>>(
            W1, W2, W1T, pk, gcnt);

        // gemm1 || partition (independent; partition blocks first so
        // fine_scatter's dependency clears earliest). Dynamic LDS 27648 B.
        gemm_part_kernel<<<pblocks + mblocks, 256, (64 + 128) * 72 * 2, stream>>>(
            x, W1T, Y1h, nN, rows, cols, vals, gcnt, eb1, nE, nB, pblocks);

        fine_scatter_kernel<<<nB, 1024, 0, stream>>>(gcnt, eb1, eb2, off2, nN);

        // Y2 = fp16(relu(b1 + spmm(Y1)) @ W2)   [fused]
        spmm_fused_kernel<<<sblocks, 256, 0, stream>>>(off2, eb2, Y1h, b1, pk, Y2h, nN);
        // out = b2 + spmm(Y2)
        spmm_csr64_kernel<<<sblocks, 256, 0, stream>>>(off2, eb2, Y2h, b2, out, nN);
    } else {
        // ---- fallback: atomic path (own ws layout) ----
        char* v = (char*)d_ws;
        __half* fY1h = (__half*)v;  v += (size_t)nN * 128 * 2;
        float*  fH1  = (float*)v;   v += (size_t)nN * 128 * 4;
        __half* fW1T = (__half*)v;  v += (size_t)256 * 128 * 2;
        __half* fW2T = (__half*)v;  v += (size_t)128 * 64 * 2;

        transpose_w_kernel<<<(256 * 128 + 255) / 256, 256, 0, stream>>>(W1, fW1T, 256, 128);
        transpose_w_kernel<<<(128 * 64 + 255) / 256, 256, 0, stream>>>(W2, fW2T, 128, 64);
        gemm_mfma_kernel<128, 256, false><<<mblocks, 256, 0, stream>>>(x, fW1T, fY1h, nN);
        size_t totH1 = (size_t)nN * 128;
        init_bias_kernel<<<(int)((totH1 + 255) / 256), 256, 0, stream>>>(fH1, b1, 127, totH1);
        spmm_atomic_kernel<128><<<eblocks4, 256, 0, stream>>>(rows, cols, vals, fY1h, fH1, nE);
        gemm_mfma_kernel<64, 128, true><<<mblocks, 256, 0, stream>>>(fH1, fW2T, fY1h, nN);
        size_t totOut = (size_t)nN * 64;
        init_bias_kernel<<<(int)((totOut + 255) / 256), 256, 0, stream>>>(out, b2, 63, totOut);
        spmm_atomic_kernel<64><<<eblocks4, 256, 0, stream>>>(rows, cols, vals, fY1h, out, nE);
    }
}